// Round 2
// baseline (397.507 us; speedup 1.0000x reference)
//
#include <hip/hip_runtime.h>
#include <stdint.h>

#define N_MEM   50000
#define DDIM    1024
#define MQ      256
#define BK      64
#define NT      64
#define NCHUNK  ((N_MEM + NT - 1) / NT)   // 782
#define KCHUNKS (DDIM / BK)               // 16
#define THREADS 256
#define SIM_TH  0.6f
#define NEGINF  (-3.0e38f)

typedef __attribute__((ext_vector_type(8))) short short8;
typedef __attribute__((ext_vector_type(4))) float f32x4;

// fp32 -> bf16 round-to-nearest-even
__device__ __forceinline__ unsigned short f2bf(float x) {
  union { float f; unsigned int u; } a; a.f = x;
  unsigned int r = (a.u + 0x7fffu + ((a.u >> 16) & 1u)) >> 16;
  return (unsigned short)r;
}

// async global->LDS DMA, 16 B per lane; LDS dst = wave-uniform base + lane*16
__device__ __forceinline__ void dma16(const void* g, void* l) {
  __builtin_amdgcn_global_load_lds(
      (const __attribute__((address_space(1))) unsigned int*)g,
      (__attribute__((address_space(3))) unsigned int*)l, 16, 0, 0);
}

// ---------------------------------------------------------------------------
// Kernel 0: query fp32 -> bf16, chunk-major + XOR-swizzled (16B blocks), qnorm
// layout: qbf[kc][m][ (blk ^ (m&7)) ]  with blk = 8-bf16 (16 B) blocks, 8/row
// ---------------------------------------------------------------------------
__global__ __launch_bounds__(256) void prep_kernel(
    const float* __restrict__ q, unsigned short* __restrict__ qbf,
    float* __restrict__ qnorm) {
  const int m = blockIdx.x;
  const int t = threadIdx.x;
  const f32x4 v = *(const f32x4*)(q + (size_t)m * DDIM + t * 4);
  const int k = t * 4;
  const int kc = k >> 6;
  const int jb = (k >> 3) & 7;
  const int half = (k >> 2) & 1;
  ushort4 h;
  h.x = f2bf(v.x); h.y = f2bf(v.y); h.z = f2bf(v.z); h.w = f2bf(v.w);
  *(ushort4*)(qbf + (size_t)kc * (MQ * BK) + m * 64 + ((jb ^ (m & 7)) * 8) + half * 4) = h;

  float ss = v.x * v.x + v.y * v.y + v.z * v.z + v.w * v.w;
  #pragma unroll
  for (int off = 1; off < 64; off <<= 1) ss += __shfl_xor(ss, off);
  __shared__ float red[4];
  if ((t & 63) == 0) red[t >> 6] = ss;
  __syncthreads();
  if (t == 0) qnorm[m] = sqrtf(red[0] + red[1] + red[2] + red[3]);
}

// ---------------------------------------------------------------------------
// Kernel 1: fused  dots = Q @ Mem^T  (bf16 MFMA) + mnorm + per-chunk argmax
// WG tile 256x64, wave tile 64x64 (4x4 of 16x16x32), K-loop BK=64.
// Software-pipelined: A (query) double-buffered in LDS via global_load_lds
// issued one iteration ahead; B (memories) prefetched one iteration ahead
// through VGPRs. 72 KB LDS -> 2 blocks/CU.
// ---------------------------------------------------------------------------
__global__ __launch_bounds__(THREADS, 2) void sim_argmax_kernel(
    const float* __restrict__ mem, const unsigned short* __restrict__ qbf,
    float* __restrict__ pmax, int* __restrict__ pidx) {
  __shared__ unsigned short As[2][MQ * BK];   // 2 x 32 KB, swizzled (DMA'd)
  __shared__ unsigned short Bs[NT * BK];      // 8 KB, swizzled (reused for rinv)

  const int t = threadIdx.x;
  const int lane = t & 63;
  const int w = t >> 6;
  const int c = blockIdx.x;
  const int n0 = c * NT;

  const int br = t >> 2;   // B staging row 0..63 (fixed per thread across K)
  const int bj = t & 3;    // 4 threads per row

  f32x4 acc[4][4];
  #pragma unroll
  for (int mi = 0; mi < 4; ++mi)
    #pragma unroll
    for (int ni = 0; ni < 4; ++ni)
      acc[mi][ni] = (f32x4){0.f, 0.f, 0.f, 0.f};

  const bool browok = (n0 + br) < N_MEM;
  const float* browp = mem + (size_t)(n0 + br) * DDIM;
  float sumsq = 0.f;

  const int quad = lane >> 4, li = lane & 15;

  // ---- prologue: issue A-DMA(0) and B-load(0) ----
  #pragma unroll
  for (int i = 0; i < 8; ++i)
    dma16(qbf + i * 2048 + t * 8, (void*)(&As[0][i * 2048 + t * 8]));

  f32x4 v[4];
  #pragma unroll
  for (int i = 0; i < 4; ++i) {
    if (browok) v[i] = *(const f32x4*)(browp + bj * 4 + i * 16);
    else        v[i] = (f32x4){0.f, 0.f, 0.f, 0.f};
  }

  #pragma unroll
  for (int kc = 0; kc < KCHUNKS; ++kc) {
    const int buf = kc & 1;

    // ---- write B(kc) regs -> Bs (swizzled), fused sumsq ----
    #pragma unroll
    for (int i = 0; i < 4; ++i) {
      sumsq += v[i].x * v[i].x + v[i].y * v[i].y + v[i].z * v[i].z + v[i].w * v[i].w;
      const int col = i * 16 + bj * 4;
      const int jb = col >> 3;
      const int half = (col >> 2) & 1;
      ushort4 h;
      h.x = f2bf(v[i].x); h.y = f2bf(v[i].y); h.z = f2bf(v[i].z); h.w = f2bf(v[i].w);
      *(ushort4*)(Bs + br * 64 + ((jb ^ (br & 7)) * 8) + half * 4) = h;
    }
    __syncthreads();   // B1: A-DMA(kc) drained (issued last iter), B writes visible

    // ---- prefetch for kc+1: A-DMA into other buffer, B into regs ----
    if (kc + 1 < KCHUNKS) {
      const unsigned short* qc = qbf + (size_t)(kc + 1) * (MQ * BK);
      #pragma unroll
      for (int i = 0; i < 8; ++i)
        dma16(qc + i * 2048 + t * 8, (void*)(&As[buf ^ 1][i * 2048 + t * 8]));
      const float* p = browp + (kc + 1) * BK + bj * 4;
      #pragma unroll
      for (int i = 0; i < 4; ++i) {
        if (browok) v[i] = *(const f32x4*)(p + i * 16);
        else        v[i] = (f32x4){0.f, 0.f, 0.f, 0.f};
      }
    }

    // ---- MFMA: 2 K-steps x 16 MFMA, 8 ds_read_b128 per step ----
    #pragma unroll
    for (int s = 0; s < 2; ++s) {
      const int kb = s * 4 + quad;
      short8 af[4], bfr[4];
      #pragma unroll
      for (int mi = 0; mi < 4; ++mi) {
        const int m = w * 64 + mi * 16 + li;
        af[mi] = *(const short8*)(&As[buf][m * 64 + ((kb ^ (m & 7)) * 8)]);
      }
      #pragma unroll
      for (int ni = 0; ni < 4; ++ni) {
        const int n = ni * 16 + li;
        bfr[ni] = *(const short8*)(Bs + n * 64 + ((kb ^ (n & 7)) * 8));
      }
      #pragma unroll
      for (int mi = 0; mi < 4; ++mi)
        #pragma unroll
        for (int ni = 0; ni < 4; ++ni)
          acc[mi][ni] = __builtin_amdgcn_mfma_f32_16x16x32_bf16(
              af[mi], bfr[ni], acc[mi][ni], 0, 0, 0);
    }
    __syncthreads();   // B2: drains prefetch (overlapped by MFMA); guards Bs overwrite
  }

  // ---- mnorm: reduce sumsq across the 4 staging threads of each row ----
  // Bs no longer needed for fragments; reuse its storage for rinv.
  float* rinv = (float*)Bs;
  sumsq += __shfl_xor(sumsq, 1);
  sumsq += __shfl_xor(sumsq, 2);
  if (bj == 0) rinv[br] = browok ? rsqrtf(fmaxf(sumsq, 1e-30f)) : 0.f;
  __syncthreads();

  // ---- per-row argmax of dot/mnorm over this chunk's 64 cols ----
  {
    float rv[4]; int gn[4];
    #pragma unroll
    for (int ni = 0; ni < 4; ++ni) {
      const int nl = ni * 16 + li;
      rv[ni] = rinv[nl];
      gn[ni] = n0 + nl;
    }
    #pragma unroll
    for (int mi = 0; mi < 4; ++mi) {
      #pragma unroll
      for (int r = 0; r < 4; ++r) {
        float best = NEGINF; int bi = 0x7fffffff;
        #pragma unroll
        for (int ni = 0; ni < 4; ++ni) {
          float vv = acc[mi][ni][r] * rv[ni];
          vv = (gn[ni] < N_MEM) ? vv : NEGINF;
          if (vv > best || (vv == best && gn[ni] < bi)) { best = vv; bi = gn[ni]; }
        }
        #pragma unroll
        for (int off = 1; off < 16; off <<= 1) {
          const float ov = __shfl_xor(best, off);
          const int oi = __shfl_xor(bi, off);
          if (ov > best || (ov == best && oi < bi)) { best = ov; bi = oi; }
        }
        if (li == 0) {
          const int row = w * 64 + mi * 16 + quad * 4 + r;
          pmax[(size_t)c * MQ + row] = best;
          pidx[(size_t)c * MQ + row] = bi;
        }
      }
    }
  }
}

// ---------------------------------------------------------------------------
// Kernel 2: global argmax over 782 chunks, threshold, decode (or zeros)
// ---------------------------------------------------------------------------
__global__ __launch_bounds__(256) void finalize_kernel(
    const float* __restrict__ mem, const float* __restrict__ dec_w,
    const float* __restrict__ dec_b, const float* __restrict__ qnorm,
    const float* __restrict__ pmax, const int* __restrict__ pidx,
    float* __restrict__ out) {
  const int b = blockIdx.x;
  const int t = threadIdx.x;
  float best = NEGINF; int bi = 0x7fffffff;
  for (int c = t; c < NCHUNK; c += 256) {
    const float v = pmax[(size_t)c * MQ + b];
    const int i = pidx[(size_t)c * MQ + b];
    if (v > best || (v == best && i < bi)) { best = v; bi = i; }
  }
  #pragma unroll
  for (int off = 1; off < 64; off <<= 1) {
    const float ov = __shfl_xor(best, off);
    const int oi = __shfl_xor(bi, off);
    if (ov > best || (ov == best && oi < bi)) { best = ov; bi = oi; }
  }
  __shared__ float sv[4]; __shared__ int si[4];
  __shared__ float sbest; __shared__ int sbi;
  if ((t & 63) == 0) { sv[t >> 6] = best; si[t >> 6] = bi; }
  __syncthreads();
  if (t == 0) {
    float bb = sv[0]; int ii = si[0];
    #pragma unroll
    for (int k = 1; k < 4; ++k)
      if (sv[k] > bb || (sv[k] == bb && si[k] < ii)) { bb = sv[k]; ii = si[k]; }
    sbest = bb; sbi = ii;
  }
  __syncthreads();

  const float sim = sbest / fmaxf(qnorm[b], 1e-20f);  // sbest = dot/mnorm
  if (sim > SIM_TH) {
    __shared__ float ms[DDIM];
    *(f32x4*)(ms + t * 4) = *(const f32x4*)(mem + (size_t)sbi * DDIM + t * 4);
    __syncthreads();
    #pragma unroll
    for (int jj = 0; jj < 4; ++jj) {
      const int j = jj * 256 + t;
      const float* wr = dec_w + (size_t)j * DDIM;
      float s = dec_b[j];
      for (int k = 0; k < DDIM; k += 4) {
        const f32x4 a = *(const f32x4*)(ms + k);
        const f32x4 ww = *(const f32x4*)(wr + k);
        s += a.x * ww.x + a.y * ww.y + a.z * ww.z + a.w * ww.w;
      }
      out[(size_t)b * DDIM + j] = s;
    }
  } else {
    *(f32x4*)(out + (size_t)b * DDIM + t * 4) = (f32x4){0.f, 0.f, 0.f, 0.f};
  }
}

// ---------------------------------------------------------------------------
extern "C" void kernel_launch(void* const* d_in, const int* in_sizes, int n_in,
                              void* d_out, int out_size, void* d_ws, size_t ws_size,
                              hipStream_t stream) {
  const float* query = (const float*)d_in[0];   // [256,1024]
  const float* mem   = (const float*)d_in[1];   // [50000,1024]
  const float* dec_w = (const float*)d_in[2];   // [1024,1024]
  const float* dec_b = (const float*)d_in[3];   // [1024]
  float* out = (float*)d_out;                   // [256,1024]

  char* ws = (char*)d_ws;
  unsigned short* qbf = (unsigned short*)ws;                    // 512 KB
  float* qnorm = (float*)(ws + 524288);                         // 1 KB
  float* pmax  = (float*)(ws + 525312);                         // 782*256*4
  int*   pidx  = (int*)(ws + 525312 + (size_t)NCHUNK * MQ * 4); // 782*256*4

  hipLaunchKernelGGL(prep_kernel, dim3(MQ), dim3(256), 0, stream,
                     query, qbf, qnorm);
  hipLaunchKernelGGL(sim_argmax_kernel, dim3(NCHUNK), dim3(THREADS), 0, stream,
                     mem, qbf, pmax, pidx);
  hipLaunchKernelGGL(finalize_kernel, dim3(MQ), dim3(256), 0, stream,
                     mem, dec_w, dec_b, qnorm, pmax, pidx, out);
}

// Round 3
// 375.086 us; speedup vs baseline: 1.0598x; 1.0598x over previous
//
#include <hip/hip_runtime.h>
#include <stdint.h>

#define N_MEM   50000
#define DDIM    1024
#define MQ      256
#define BK      64
#define NT      32
#define NBLK    ((N_MEM + NT - 1) / NT)   // 1563
#define KCHUNKS (DDIM / BK)               // 16
#define THREADS 256
#define SIM_TH  0.6f
#define NEGINF  (-3.0e38f)
#define ACHUNK  (MQ * BK)                 // 16384 bytes per fp8 A-chunk

typedef __attribute__((ext_vector_type(4))) float f32x4;

#if defined(__has_builtin)
#if __has_builtin(__builtin_amdgcn_cvt_pk_fp8_f32)
#define HAVE_CVT_PK_FP8 1
#endif
#endif

// float -> e4m3fn (manual fallback; truncation-level accuracy is ample here)
__device__ __forceinline__ unsigned int f2e4m3_1(float x) {
  unsigned int u = __float_as_uint(x);
  unsigned int s = (u >> 24) & 0x80u;
  unsigned int a = u & 0x7fffffffu;
  if (a >= 0x43E00000u) return s | 0x7Eu;          // clamp to 448
  if (a < 0x3C800000u) {                           // < 2^-6 -> subnormal
    float ax = __uint_as_float(a);
    unsigned int q = (unsigned int)(ax * 512.0f + 0.5f);  // step 2^-9
    return s | q;                                  // q==8 aliases to min normal
  }
  a += 0x0007FFFFu + ((a >> 20) & 1u);             // RNE at bit 20
  int E = (int)(a >> 23) - 127 + 7;
  unsigned int m = (a >> 20) & 7u;
  if (E > 15 || (E == 15 && m == 7u)) return s | 0x7Eu;
  return s | ((unsigned int)E << 3) | m;
}

// pack 4 floats -> 4 fp8 bytes (byte0 = v.x)
__device__ __forceinline__ int pack4_fp8(f32x4 v) {
#ifdef HAVE_CVT_PK_FP8
  int pk = __builtin_amdgcn_cvt_pk_fp8_f32(v.x, v.y, 0, false);
  pk = __builtin_amdgcn_cvt_pk_fp8_f32(v.z, v.w, pk, true);
  return pk;
#else
  return (int)(f2e4m3_1(v.x) | (f2e4m3_1(v.y) << 8) |
               (f2e4m3_1(v.z) << 16) | (f2e4m3_1(v.w) << 24));
#endif
}

// async global->LDS DMA, 16 B per lane; LDS dst = wave-uniform base + lane*16
__device__ __forceinline__ void dma16(const void* g, void* l) {
  __builtin_amdgcn_global_load_lds(
      (const __attribute__((address_space(1))) unsigned int*)g,
      (__attribute__((address_space(3))) unsigned int*)l, 16, 0, 0);
}

// ---------------------------------------------------------------------------
// Kernel 0: query fp32 -> fp8, chunk-major + XOR-swizzled (8B blocks), qnorm
// layout: qf8[kc][m][ byte = (kb ^ (m&7))*8 + (k&7) ], kb = (k>>3)&7
// ---------------------------------------------------------------------------
__global__ __launch_bounds__(256) void prep_kernel(
    const float* __restrict__ q, unsigned char* __restrict__ qf8,
    float* __restrict__ qnorm) {
  const int m = blockIdx.x;
  const int t = threadIdx.x;
  const f32x4 v = *(const f32x4*)(q + (size_t)m * DDIM + t * 4);
  const int kc = t >> 4;
  const int kb = (t >> 1) & 7;
  const int pk = pack4_fp8(v);
  *(int*)(qf8 + (size_t)kc * ACHUNK + m * 64 + ((kb ^ (m & 7)) * 8) + (t & 1) * 4) = pk;

  float ss = v.x * v.x + v.y * v.y + v.z * v.z + v.w * v.w;
  #pragma unroll
  for (int off = 1; off < 64; off <<= 1) ss += __shfl_xor(ss, off);
  __shared__ float red[4];
  if ((t & 63) == 0) red[t >> 6] = ss;
  __syncthreads();
  if (t == 0) qnorm[m] = sqrtf(red[0] + red[1] + red[2] + red[3]);
}

// ---------------------------------------------------------------------------
// Kernel 1: fused  dots = Q @ Mem^T  (fp8 MFMA) + mnorm + per-chunk argmax
// Block tile M=256 x N=32 x K=1024: B (32 full rows) streamed CONTIGUOUSLY
// once into LDS as fp8; A DMA'd per-K-chunk, double-buffered, prefetch dist 1.
// LDS: 2x16KB A + 32KB B + rinv = 64.1 KB -> 2 blocks/CU.
// ---------------------------------------------------------------------------
__global__ __launch_bounds__(THREADS, 2) void sim_kernel(
    const float* __restrict__ mem, const unsigned char* __restrict__ qf8,
    float* __restrict__ pmax, int* __restrict__ pidx) {
  __shared__ unsigned char As[2][ACHUNK];   // 2 x 16 KB, swizzled (DMA'd)
  __shared__ unsigned char Bs[NT * DDIM];   // 32 KB, swizzled
  __shared__ float rinv[NT];

  const int t = threadIdx.x;
  const int lane = t & 63;
  const int w = t >> 6;
  const int quad = lane >> 4, li = lane & 15;
  const int c = blockIdx.x;
  const int n0 = c * NT;

  f32x4 acc[4][2];
  #pragma unroll
  for (int mi = 0; mi < 4; ++mi)
    #pragma unroll
    for (int ni = 0; ni < 2; ++ni)
      acc[mi][ni] = (f32x4){0.f, 0.f, 0.f, 0.f};

  // ---- issue A-DMA(0) first: overlaps the whole B streaming phase ----
  #pragma unroll
  for (int i = 0; i < 4; ++i)
    dma16(qf8 + i * 4096 + t * 16, (void*)(&As[0][i * 4096 + t * 16]));

  // ---- B phase: stream 32 full rows (4 KB each, contiguous), cvt fp8 ----
  // wave w handles rows w*8 .. w*8+7; one row = 4 sub-passes of 1 KB/wave
  for (int p = 0; p < 8; ++p) {
    const int r = w * 8 + p;
    const int gn = n0 + r;
    const bool ok = gn < N_MEM;
    const float* rp = mem + (size_t)gn * DDIM;
    float ss = 0.f;
    #pragma unroll
    for (int sp = 0; sp < 4; ++sp) {
      f32x4 v;
      if (ok) v = *(const f32x4*)(rp + sp * 256 + lane * 4);
      else    v = (f32x4){0.f, 0.f, 0.f, 0.f};
      ss += v.x * v.x + v.y * v.y + v.z * v.z + v.w * v.w;
      const int col = sp * 256 + lane * 4;
      const int kb = col >> 3;
      const int kb2 = (kb & ~7) | ((kb ^ r) & 7);
      *(int*)(Bs + r * DDIM + kb2 * 8 + (col & 7)) = pack4_fp8(v);
    }
    #pragma unroll
    for (int off = 1; off < 64; off <<= 1) ss += __shfl_xor(ss, off);
    if (lane == 0) rinv[r] = ok ? rsqrtf(fmaxf(ss, 1e-30f)) : 0.f;
  }
  __syncthreads();   // drains A-DMA(0) + B writes + rinv

  // ---- K-loop: 16 chunks, one barrier each, A-DMA prefetch dist 1 ----
  for (int kc = 0; kc < KCHUNKS; ++kc) {
    const unsigned char* a_cur = As[kc & 1];
    if (kc + 1 < KCHUNKS) {
      const unsigned char* qc = qf8 + (size_t)(kc + 1) * ACHUNK;
      unsigned char* dst = As[(kc + 1) & 1];
      #pragma unroll
      for (int i = 0; i < 4; ++i)
        dma16(qc + i * 4096 + t * 16, (void*)(dst + i * 4096 + t * 16));
    }
    #pragma unroll
    for (int s = 0; s < 2; ++s) {
      const int kb = s * 4 + quad;            // 8B-block within 64B A-row
      const int kbg = kc * 8 + kb;            // global 8B-block for B
      long af[4], bf[2];
      #pragma unroll
      for (int mi = 0; mi < 4; ++mi) {
        const int m = w * 64 + mi * 16 + li;
        af[mi] = *(const long*)(a_cur + m * 64 + ((kb ^ (m & 7)) * 8));
      }
      #pragma unroll
      for (int ni = 0; ni < 2; ++ni) {
        const int n = ni * 16 + li;
        const int kb2 = (kbg & ~7) | ((kbg ^ (n & 7)) & 7);
        bf[ni] = *(const long*)(Bs + n * DDIM + kb2 * 8);
      }
      #pragma unroll
      for (int mi = 0; mi < 4; ++mi)
        #pragma unroll
        for (int ni = 0; ni < 2; ++ni)
          acc[mi][ni] = __builtin_amdgcn_mfma_f32_16x16x32_fp8_fp8(
              af[mi], bf[ni], acc[mi][ni], 0, 0, 0);
    }
    __syncthreads();   // drains prefetch DMA (overlapped); guards As reuse
  }

  // ---- per-row argmax of dot*rinv over this chunk's 32 cols ----
  {
    float rv[2]; int gn[2];
    #pragma unroll
    for (int ni = 0; ni < 2; ++ni) {
      const int nl = ni * 16 + li;
      rv[ni] = rinv[nl];
      gn[ni] = n0 + nl;
    }
    #pragma unroll
    for (int mi = 0; mi < 4; ++mi) {
      #pragma unroll
      for (int r = 0; r < 4; ++r) {
        float best = NEGINF; int bi = 0x7fffffff;
        #pragma unroll
        for (int ni = 0; ni < 2; ++ni) {
          float vv = acc[mi][ni][r] * rv[ni];
          vv = (gn[ni] < N_MEM) ? vv : NEGINF;
          if (vv > best || (vv == best && gn[ni] < bi)) { best = vv; bi = gn[ni]; }
        }
        #pragma unroll
        for (int off = 1; off < 16; off <<= 1) {
          const float ov = __shfl_xor(best, off);
          const int oi = __shfl_xor(bi, off);
          if (ov > best || (ov == best && oi < bi)) { best = ov; bi = oi; }
        }
        if (li == 0) {
          const int row = w * 64 + mi * 16 + quad * 4 + r;
          pmax[(size_t)row * NBLK + c] = best;   // row-major for finalize
          pidx[(size_t)row * NBLK + c] = bi;
        }
      }
    }
  }
}

// ---------------------------------------------------------------------------
// Kernel 2: global argmax over 1563 chunks, threshold, decode (or zeros)
// ---------------------------------------------------------------------------
__global__ __launch_bounds__(256) void finalize_kernel(
    const float* __restrict__ mem, const float* __restrict__ dec_w,
    const float* __restrict__ dec_b, const float* __restrict__ qnorm,
    const float* __restrict__ pmax, const int* __restrict__ pidx,
    float* __restrict__ out) {
  const int b = blockIdx.x;
  const int t = threadIdx.x;
  float best = NEGINF; int bi = 0x7fffffff;
  for (int c = t; c < NBLK; c += 256) {
    const float v = pmax[(size_t)b * NBLK + c];
    const int i = pidx[(size_t)b * NBLK + c];
    if (v > best || (v == best && i < bi)) { best = v; bi = i; }
  }
  #pragma unroll
  for (int off = 1; off < 64; off <<= 1) {
    const float ov = __shfl_xor(best, off);
    const int oi = __shfl_xor(bi, off);
    if (ov > best || (ov == best && oi < bi)) { best = ov; bi = oi; }
  }
  __shared__ float sv[4]; __shared__ int si[4];
  __shared__ float sbest; __shared__ int sbi;
  if ((t & 63) == 0) { sv[t >> 6] = best; si[t >> 6] = bi; }
  __syncthreads();
  if (t == 0) {
    float bb = sv[0]; int ii = si[0];
    #pragma unroll
    for (int k = 1; k < 4; ++k)
      if (sv[k] > bb || (sv[k] == bb && si[k] < ii)) { bb = sv[k]; ii = si[k]; }
    sbest = bb; sbi = ii;
  }
  __syncthreads();

  const float sim = sbest / fmaxf(qnorm[b], 1e-20f);  // sbest = dot/mnorm
  if (sim > SIM_TH) {
    __shared__ float ms[DDIM];
    *(f32x4*)(ms + t * 4) = *(const f32x4*)(mem + (size_t)sbi * DDIM + t * 4);
    __syncthreads();
    #pragma unroll
    for (int jj = 0; jj < 4; ++jj) {
      const int j = jj * 256 + t;
      const float* wr = dec_w + (size_t)j * DDIM;
      float s = dec_b[j];
      for (int k = 0; k < DDIM; k += 4) {
        const f32x4 a = *(const f32x4*)(ms + k);
        const f32x4 ww = *(const f32x4*)(wr + k);
        s += a.x * ww.x + a.y * ww.y + a.z * ww.z + a.w * ww.w;
      }
      out[(size_t)b * DDIM + j] = s;
    }
  } else {
    *(f32x4*)(out + (size_t)b * DDIM + t * 4) = (f32x4){0.f, 0.f, 0.f, 0.f};
  }
}

// ---------------------------------------------------------------------------
extern "C" void kernel_launch(void* const* d_in, const int* in_sizes, int n_in,
                              void* d_out, int out_size, void* d_ws, size_t ws_size,
                              hipStream_t stream) {
  const float* query = (const float*)d_in[0];   // [256,1024]
  const float* mem   = (const float*)d_in[1];   // [50000,1024]
  const float* dec_w = (const float*)d_in[2];   // [1024,1024]
  const float* dec_b = (const float*)d_in[3];   // [1024]
  float* out = (float*)d_out;                   // [256,1024]

  char* ws = (char*)d_ws;
  unsigned char* qf8 = (unsigned char*)ws;                 // 256 KB (16 chunks)
  float* qnorm = (float*)(ws + 262144);                    // 1 KB
  float* pmax  = (float*)(ws + 263168);                    // 256*1563*4 = 1.6 MB
  int*   pidx  = (int*)(ws + 263168 + (size_t)MQ * NBLK * 4);

  hipLaunchKernelGGL(prep_kernel, dim3(MQ), dim3(256), 0, stream,
                     query, qf8, qnorm);
  hipLaunchKernelGGL(sim_kernel, dim3(NBLK), dim3(THREADS), 0, stream,
                     mem, qf8, pmax, pidx);
  hipLaunchKernelGGL(finalize_kernel, dim3(MQ), dim3(256), 0, stream,
                     mem, dec_w, dec_b, qnorm, pmax, pidx, out);
}